// Round 18
// baseline (161.503 us; speedup 1.0000x reference)
//
#include <hip/hip_runtime.h>

namespace {
constexpr int kL0 = 16384;
constexpr int kN1 = 8195;
constexpr int kN2 = 4101;
constexpr int kThreads = 128;            // 2 waves per block
constexpr int kTS = 1024;                // outputs per tile
constexpr int kTilesPerRow = kL0 / kTS;  // 16
constexpr int SA2 = 274;                 // a2ext [O/4-6 , O/4+268)

constexpr float RLc[8] = {
     0.23037781330885523f,  0.7148465705525415f,   0.6308807679295904f,
    -0.02798376941698385f, -0.18703481171888114f,  0.030841381835986965f,
     0.032883011666982945f, -0.010597401785069032f };

// 3-level low-reconstruction bank (verified R5-R17): low[8q+r] = sum_m W[r][m]*a3[q+m]
struct WT { float w[8][7]; };
constexpr WT make_w() {
    WT W{};
    for (int r = 0; r < 8; ++r) {
        const int r2 = r >> 1, pi = r & 1;
        for (int u = 0; u < 4; ++u) {
            const float cu = RLc[6 + pi - 2 * u];
            const int k = r2 + u, k2 = k >> 1, pk = k & 1;
            for (int s = 0; s < 4; ++s) {
                const float cs = RLc[6 + pk - 2 * s];
                const int j = k2 + s, j2 = j >> 1, pj = j & 1;
                for (int t = 0; t < 4; ++t)
                    W.w[r][j2 + t] += cu * cs * RLc[6 + pj - 2 * t];
            }
        }
    }
    return W;
}

// W2 folds the a3 tap (verified R16): low[8*tid+r] = sum_{j=0..19} W2[r][j]*sa2[2*tid+j]
struct W2T { float w[8][20]; };
constexpr W2T make_w2() {
    W2T W2{};
    const WT Wt = make_w();
    for (int r = 0; r < 8; ++r)
        for (int m = 0; m < 7; ++m)
            for (int k = 0; k < 8; ++k)
                W2.w[r][2 * m + k] += Wt.w[r][m] * RLc[k];
    return W2;
}

__device__ constexpr float RL[8] = {
     0.23037781330885523f,  0.7148465705525415f,   0.6308807679295904f,
    -0.02798376941698385f, -0.18703481171888114f,  0.030841381835986965f,
     0.032883011666982945f, -0.010597401785069032f };
__device__ constexpr W2T W2 = make_w2();

typedef float vfloat4 __attribute__((ext_vector_type(4)));
} // namespace

__device__ __forceinline__ int reflect(int g, int N) {
    if (g < 0)  g = -1 - g;
    if (g >= N) g = 2 * N - 1 - g;
    return g;
}

// fused level-1+2 pair (verified R15/R16): from x[base .. base+27] (16B-aligned)
__device__ __forceinline__ float2 a2_pair(const float* __restrict__ base) {
    const float4* __restrict__ p = reinterpret_cast<const float4*>(base);
    float e[28];
    #pragma unroll
    for (int c = 0; c < 7; ++c) {
        const float4 v = p[c];
        e[4 * c] = v.x; e[4 * c + 1] = v.y;
        e[4 * c + 2] = v.z; e[4 * c + 3] = v.w;
    }
    float a1r[10];
    #pragma unroll
    for (int u = 0; u < 10; ++u) {
        float s = e[2 * u + 2] * RL[0];
        #pragma unroll
        for (int k = 1; k < 8; ++k)
            s = fmaf(e[2 * u + 2 + k], RL[k], s);
        a1r[u] = s;
    }
    float o[2];
    #pragma unroll
    for (int i = 0; i < 2; ++i) {
        float s = a1r[2 * i] * RL[0];
        #pragma unroll
        for (int k = 1; k < 8; ++k)
            s = fmaf(a1r[2 * i + k], RL[k], s);
        o[i] = s;
    }
    return make_float2(o[0], o[1]);
}

// boundary a1: a1ext[w] with full reflection at a1 and x levels
// (identical sums to the R13-verified staged edge path)
__device__ __forceinline__ float a1_reflect(const float* __restrict__ xr, int w) {
    const int i = reflect(w, kN1);
    float s = 0.f;
    #pragma unroll
    for (int j = 0; j < 8; ++j)
        s = fmaf(xr[reflect(2 * i - 6 + j, kL0)], RL[j], s);
    return s;
}

// boundary a2ext[g]: g may be outside [0,kN2)
__device__ __forceinline__ float a2_slow(const float* __restrict__ xr, int g) {
    const int g2 = reflect(g, kN2);
    float s = 0.f;
    #pragma unroll
    for (int k = 0; k < 8; ++k)
        s = fmaf(a1_reflect(xr, 2 * g2 - 6 + k), RL[k], s);
    return s;
}

// barrier with LDS-visibility only (no vmcnt drain) — R10/R12-R17-verified
__device__ __forceinline__ void bar_lgkm() {
    asm volatile("s_waitcnt lgkmcnt(0)" ::: "memory");
    __builtin_amdgcn_s_barrier();
    asm volatile("" ::: "memory");
}

__global__ void __launch_bounds__(kThreads, 8)
wavelet_v18(const float* __restrict__ x, float* __restrict__ out, int rows) {
    __shared__ __align__(16) float sa2[SA2 + 2];

    const int tid  = threadIdx.x;
    const int row  = blockIdx.x >> 4;         // 16 tiles per row
    const int tile = blockIdx.x & 15;
    const int O    = tile << 10;
    const int XB   = O - 44;
    const int B0   = (O >> 2) - 6;
    const float* __restrict__ xr = x + (size_t)row * kL0;

    // ---- hoisted final-phase x re-read: issue first, consume last ----
    const float4* xr4 = reinterpret_cast<const float4*>(xr + O + 8 * tid);
    const float4 xv0 = xr4[0], xv1 = xr4[1];

    // ---- pass 0: m0 = 2*tid (m 0..255), fast iff x-window in-bounds ----
    {
        const int m0 = 2 * tid;
        const int wl = XB + 4 * m0;
        if (wl >= 0 && wl + 27 < kL0) {
            const float2 o = a2_pair(xr + wl);
            *reinterpret_cast<float2*>(&sa2[m0]) = o;
        }
    }
    // ---- pass 1: wave-0 lanes 0..8 fast (m 256..273); wave-1 lanes 0..5
    //      handle the <=12 boundary values in edge tiles ----
    if (tid < 9) {
        const int m0 = 256 + 2 * tid;
        const int wl = XB + 4 * m0;
        if (wl >= 0 && wl + 27 < kL0) {
            const float2 o = a2_pair(xr + wl);
            *reinterpret_cast<float2*>(&sa2[m0]) = o;
        }
    } else if (tid >= 64 && tid < 70) {
        int sb = -1;
        if (tile == 0)                     sb = 0;     // m 0..11 (window < 0)
        else if (tile == kTilesPerRow - 1) sb = 262;   // m 262..273 (window > end)
        if (sb >= 0) {
            const int m0 = sb + 2 * (tid - 64);
            sa2[m0]     = a2_slow(xr, B0 + m0);
            sa2[m0 + 1] = a2_slow(xr, B0 + m0 + 1);
        }
    }
    bar_lgkm();

    // ---- final: low[8*tid+r] = sum_j W2[r][j]*sa2[2*tid+j]; high = x - low ----
    {
        float b[20];
        #pragma unroll
        for (int j2 = 0; j2 < 10; ++j2) {
            const float2 v = *reinterpret_cast<const float2*>(&sa2[2 * tid + 2 * j2]);
            b[2 * j2]     = v.x;
            b[2 * j2 + 1] = v.y;
        }
        float lo[8];
        #pragma unroll
        for (int r = 0; r < 8; ++r) {
            float s = b[0] * W2.w[r][0];
            #pragma unroll
            for (int j = 1; j < 20; ++j) s = fmaf(b[j], W2.w[r][j], s);
            lo[r] = s;
        }
        float* __restrict__ lowp  = out + (size_t)row * kL0 + O + 8 * tid;
        float* __restrict__ highp = lowp + (size_t)rows * kL0;
        vfloat4 l0 = {lo[0], lo[1], lo[2], lo[3]};
        vfloat4 l1 = {lo[4], lo[5], lo[6], lo[7]};
        vfloat4 h0 = {xv0.x - lo[0], xv0.y - lo[1], xv0.z - lo[2], xv0.w - lo[3]};
        vfloat4 h1 = {xv1.x - lo[4], xv1.y - lo[5], xv1.z - lo[6], xv1.w - lo[7]};
        __builtin_nontemporal_store(l0, reinterpret_cast<vfloat4*>(lowp));
        __builtin_nontemporal_store(l1, reinterpret_cast<vfloat4*>(lowp) + 1);
        __builtin_nontemporal_store(h0, reinterpret_cast<vfloat4*>(highp));
        __builtin_nontemporal_store(h1, reinterpret_cast<vfloat4*>(highp) + 1);
    }
}

extern "C" void kernel_launch(void* const* d_in, const int* in_sizes, int n_in,
                              void* d_out, int out_size, void* d_ws, size_t ws_size,
                              hipStream_t stream) {
    (void)n_in; (void)d_ws; (void)ws_size; (void)out_size;
    const float* x = (const float*)d_in[0];
    float* out = (float*)d_out;
    const int rows = in_sizes[0] / kL0;                 // 2048
    const int blocks = rows * kTilesPerRow;             // 32768
    hipLaunchKernelGGL(wavelet_v18, dim3(blocks), dim3(kThreads), 0, stream,
                       x, out, rows);
}

// Round 19
// 81.669 us; speedup vs baseline: 1.9775x; 1.9775x over previous
//
#include <hip/hip_runtime.h>

namespace {
constexpr int kL0 = 16384;
constexpr int kN1 = 8195;
constexpr int kN2 = 4101;
constexpr int kThreads = 128;            // 2 waves per block
constexpr int kTS = 1024;                // outputs per tile
constexpr int kTilesPerRow = kL0 / kTS;  // 16

// edge-path staging: sx[t] <-> x[XB+t], XB = O-44; needed t in [2, 1116)
constexpr int SXF = 1120;
constexpr int SA1 = 554;   // a1ext [O/2-18 , O/2+536)
constexpr int SA2 = 274;   // a2ext [O/4-6  , O/4+268)

constexpr float RLc[8] = {
     0.23037781330885523f,  0.7148465705525415f,   0.6308807679295904f,
    -0.02798376941698385f, -0.18703481171888114f,  0.030841381835986965f,
     0.032883011666982945f, -0.010597401785069032f };

// 3-level low-reconstruction bank (verified R5-R16): low[8q+r] = sum_m W[r][m]*a3[q+m]
struct WT { float w[8][7]; };
constexpr WT make_w() {
    WT W{};
    for (int r = 0; r < 8; ++r) {
        const int r2 = r >> 1, pi = r & 1;
        for (int u = 0; u < 4; ++u) {
            const float cu = RLc[6 + pi - 2 * u];
            const int k = r2 + u, k2 = k >> 1, pk = k & 1;
            for (int s = 0; s < 4; ++s) {
                const float cs = RLc[6 + pk - 2 * s];
                const int j = k2 + s, j2 = j >> 1, pj = j & 1;
                for (int t = 0; t < 4; ++t)
                    W.w[r][j2 + t] += cu * cs * RLc[6 + pj - 2 * t];
            }
        }
    }
    return W;
}

// W2 folds the a3 tap (verified R16): low[8*tid+r] = sum_{j=0..19} W2[r][j]*sa2[2*tid+j]
struct W2T { float w[8][20]; };
constexpr W2T make_w2() {
    W2T W2{};
    const WT Wt = make_w();
    for (int r = 0; r < 8; ++r)
        for (int m = 0; m < 7; ++m)
            for (int k = 0; k < 8; ++k)
                W2.w[r][2 * m + k] += Wt.w[r][m] * RLc[k];
    return W2;
}

__device__ constexpr float RL[8] = {
     0.23037781330885523f,  0.7148465705525415f,   0.6308807679295904f,
    -0.02798376941698385f, -0.18703481171888114f,  0.030841381835986965f,
     0.032883011666982945f, -0.010597401785069032f };
__device__ constexpr W2T W2 = make_w2();

typedef float vfloat4 __attribute__((ext_vector_type(4)));
} // namespace

__device__ __forceinline__ int reflect(int g, int N) {
    if (g < 0)  g = -1 - g;
    if (g >= N) g = 2 * N - 1 - g;
    return g;
}

// 8-tap correlation; p at EVEN float index (8B-aligned), float2 reads
__device__ __forceinline__ float tap8f2(const float* __restrict__ p) {
    const float2* q = reinterpret_cast<const float2*>(p);
    const float2 q0 = q[0], q1 = q[1], q2 = q[2], q3 = q[3];
    float s = q0.x * RL[0];
    s = fmaf(q0.y, RL[1], s); s = fmaf(q1.x, RL[2], s); s = fmaf(q1.y, RL[3], s);
    s = fmaf(q2.x, RL[4], s); s = fmaf(q2.y, RL[5], s); s = fmaf(q3.x, RL[6], s);
    s = fmaf(q3.y, RL[7], s);
    return s;
}

// barrier with LDS-visibility only (no vmcnt drain) — R10/R12-R16-verified
__device__ __forceinline__ void bar_lgkm() {
    asm volatile("s_waitcnt lgkmcnt(0)" ::: "memory");
    __builtin_amdgcn_s_barrier();
    asm volatile("" ::: "memory");
}
__device__ __forceinline__ void bar_full() {
    asm volatile("s_waitcnt vmcnt(0) lgkmcnt(0)" ::: "memory");
    __builtin_amdgcn_s_barrier();
    asm volatile("" ::: "memory");
}

__global__ void __launch_bounds__(kThreads, 4)   // 128-VGPR budget: no spills (R18 lesson)
wavelet_v19(const float* __restrict__ x, float* __restrict__ out, int rows) {
    __shared__ __align__(16) float sx [SXF];          // edge path only
    __shared__ __align__(16) float sa1[SA1 + 2];      // edge path only
    __shared__ __align__(16) float sa2[SA2 + 2];

    const int tid  = threadIdx.x;
    const int row  = blockIdx.x >> 4;         // 16 tiles per row
    const int tile = blockIdx.x & 15;
    const int O    = tile << 10;
    const int XB   = O - 44;
    const int A0   = (O >> 1) - 18;
    const int B0   = (O >> 2) - 6;
    const float* __restrict__ xr = x + (size_t)row * kL0;
    const bool edge = (tile == 0) || (tile == kTilesPerRow - 1);

    // ---- hoisted final-phase x re-read: issue first, consume last ----
    const float4* xr4 = reinterpret_cast<const float4*>(xr + O + 8 * tid);
    const float4 xv0 = xr4[0], xv1 = xr4[1];

    if (!edge) {
        // ==== interior: levels 1+2 in registers; sa2 is the only LDS write ====
        // pass 0: m0 = 2*tid (0..254); pass 1: m0 = 256+2*tid (tid<9)
        #pragma unroll
        for (int pass = 0; pass < 2; ++pass) {
            const int m0 = (pass == 0) ? (2 * tid) : (256 + 2 * tid);
            if (pass == 0 || tid < 9) {
                // e[d] = x[XB + 4*m0 + d], d in [0,28); base 16B-aligned
                const float4* __restrict__ p =
                    reinterpret_cast<const float4*>(xr + XB + 4 * m0);
                float e[28];
                #pragma unroll
                for (int c = 0; c < 7; ++c) {
                    const float4 v = p[c];
                    e[4 * c] = v.x; e[4 * c + 1] = v.y;
                    e[4 * c + 2] = v.z; e[4 * c + 3] = v.w;
                }
                // a1 local u = 0..9: a1[A0+2m0+u], window e[2u+2 .. 2u+9]
                float a1r[10];
                #pragma unroll
                for (int u = 0; u < 10; ++u) {
                    float s = e[2 * u + 2] * RL[0];
                    #pragma unroll
                    for (int k = 1; k < 8; ++k)
                        s = fmaf(e[2 * u + 2 + k], RL[k], s);
                    a1r[u] = s;
                }
                // a2[B0+m0+i], i=0,1: window a1r[2i .. 2i+7]
                float o[2];
                #pragma unroll
                for (int i = 0; i < 2; ++i) {
                    float s = a1r[2 * i] * RL[0];
                    #pragma unroll
                    for (int k = 1; k < 8; ++k)
                        s = fmaf(a1r[2 * i + k], RL[k], s);
                    o[i] = s;
                }
                *reinterpret_cast<float2*>(&sa2[m0]) = make_float2(o[0], o[1]);
            }
        }
        bar_lgkm();
    } else {
        // ==== edge: R13-verified staged pyramid with per-level reflection ====
        const int t0  = (tile == 0) ? 44 : 4;
        const int thi = (tile == 0) ? 1116 : 1068;
        const int Nv  = (thi - t0) >> 2;
        for (int v = tid; v < Nv; v += kThreads) {
            const float4 val = *reinterpret_cast<const float4*>(xr + XB + t0 + 4 * v);
            sx[t0 + 4 * v]     = val.x; sx[t0 + 4 * v + 1] = val.y;
            sx[t0 + 4 * v + 2] = val.z; sx[t0 + 4 * v + 3] = val.w;
        }
        for (int t = 2 + tid; t < 1116; t += kThreads)
            if (t < t0 || t >= thi)
                sx[t] = xr[reflect(XB + t, kL0)];
        bar_full();

        for (int m = tid; m < SA1; m += kThreads) {
            const int g  = A0 + m;
            const int mh = (g >= 0 && g < kN1) ? m : (reflect(g, kN1) - A0);
            sa1[m] = tap8f2(&sx[2 * mh + 2]);
        }
        bar_lgkm();

        for (int m = tid; m < SA2; m += kThreads) {
            const int g = B0 + m;
            const int j = (g >= 0 && g < kN2) ? m : (reflect(g, kN2) - B0);
            sa2[m] = tap8f2(&sa1[2 * j]);
        }
        bar_lgkm();
    }

    // ---- final: low[8*tid+r] = sum_j W2[r][j]*sa2[2*tid+j]; high = x - low ----
    {
        float b[20];
        #pragma unroll
        for (int j2 = 0; j2 < 10; ++j2) {
            const float2 v = *reinterpret_cast<const float2*>(&sa2[2 * tid + 2 * j2]);
            b[2 * j2]     = v.x;
            b[2 * j2 + 1] = v.y;
        }
        float lo[8];
        #pragma unroll
        for (int r = 0; r < 8; ++r) {
            float s = b[0] * W2.w[r][0];
            #pragma unroll
            for (int j = 1; j < 20; ++j) s = fmaf(b[j], W2.w[r][j], s);
            lo[r] = s;
        }
        float* __restrict__ lowp  = out + (size_t)row * kL0 + O + 8 * tid;
        float* __restrict__ highp = lowp + (size_t)rows * kL0;
        vfloat4 l0 = {lo[0], lo[1], lo[2], lo[3]};
        vfloat4 l1 = {lo[4], lo[5], lo[6], lo[7]};
        vfloat4 h0 = {xv0.x - lo[0], xv0.y - lo[1], xv0.z - lo[2], xv0.w - lo[3]};
        vfloat4 h1 = {xv1.x - lo[4], xv1.y - lo[5], xv1.z - lo[6], xv1.w - lo[7]};
        __builtin_nontemporal_store(l0, reinterpret_cast<vfloat4*>(lowp));
        __builtin_nontemporal_store(l1, reinterpret_cast<vfloat4*>(lowp) + 1);
        __builtin_nontemporal_store(h0, reinterpret_cast<vfloat4*>(highp));
        __builtin_nontemporal_store(h1, reinterpret_cast<vfloat4*>(highp) + 1);
    }
}

extern "C" void kernel_launch(void* const* d_in, const int* in_sizes, int n_in,
                              void* d_out, int out_size, void* d_ws, size_t ws_size,
                              hipStream_t stream) {
    (void)n_in; (void)d_ws; (void)ws_size; (void)out_size;
    const float* x = (const float*)d_in[0];
    float* out = (float*)d_out;
    const int rows = in_sizes[0] / kL0;                 // 2048
    const int blocks = rows * kTilesPerRow;             // 32768
    hipLaunchKernelGGL(wavelet_v19, dim3(blocks), dim3(kThreads), 0, stream,
                       x, out, rows);
}